// Round 1
// baseline (329.566 us; speedup 1.0000x reference)
//
#include <hip/hip_runtime.h>

typedef _Float16 f16;
typedef f16 f16x8 __attribute__((ext_vector_type(8)));
typedef float f32x4 __attribute__((ext_vector_type(4)));

#define PI_F 3.14159265358979323846f

constexpr int TP = 256;          // points per block
constexpr int FSTR = 136;        // LDS row stride in f16 (272 B, 16B-aligned, bank-skewed)
constexpr int PLANE_ELEMS = 128 * 128 * 16;
constexpr int LINE_ELEMS = 128 * 16;

__device__ __forceinline__ float4 ld4(const float* p) { return *(const float4*)p; }

__device__ __forceinline__ float4 bilerp4(float4 a, float4 b, float4 c, float4 d,
                                          float w00, float w01, float w10, float w11) {
    float4 r;
    r.x = a.x * w00 + b.x * w01 + c.x * w10 + d.x * w11;
    r.y = a.y * w00 + b.y * w01 + c.y * w10 + d.y * w11;
    r.z = a.z * w00 + b.z * w01 + c.z * w10 + d.z * w11;
    r.w = a.w * w00 + b.w * w01 + c.w * w10 + d.w * w11;
    return r;
}

__device__ __forceinline__ float4 lerp4(float4 a, float4 b, float t) {
    float4 r;
    r.x = a.x * (1.f - t) + b.x * t;
    r.y = a.y * (1.f - t) + b.y * t;
    r.z = a.z * (1.f - t) + b.z * t;
    r.w = a.w * (1.f - t) + b.w * t;
    return r;
}

// ---------------------------------------------------------------------------
// Prep kernel 1: fold basis into W1, convert weights to f16, transpose lines.
// W1p [128][96] f16: cols 0..47 = W1[:, :27] @ basis_W  (pl48 path)
//                    cols 48..50 = W1[:, 27..29] (ray), 51..86 = W1[:, 30..65] (enc), 87..95 = 0
// W2h [128][128] f16 = W2.  W3p [16][128] f16: rows 0..2 = W3, rest 0.
// linesT [6][128][16] f32: [plane][l][c] from [plane][c][l].
// ---------------------------------------------------------------------------
__global__ void prep_small(const float* __restrict__ W1, const float* __restrict__ basisW,
                           const float* __restrict__ W2, const float* __restrict__ W3,
                           const float* __restrict__ dlines, const float* __restrict__ clines,
                           f16* __restrict__ W1p, f16* __restrict__ W2h, f16* __restrict__ W3p,
                           float* __restrict__ linesT) {
    int t = blockIdx.x * 256 + threadIdx.x;
    if (t < 128 * 96) {
        int r = t / 96, c = t % 96;
        float v = 0.f;
        if (c < 48) {
            for (int m = 0; m < 27; m++) v += W1[r * 66 + m] * basisW[m * 48 + c];
        } else if (c < 51) {
            v = W1[r * 66 + 27 + (c - 48)];
        } else if (c < 87) {
            v = W1[r * 66 + 30 + (c - 51)];
        }
        W1p[t] = (f16)v;
        return;
    }
    t -= 128 * 96;
    if (t < 128 * 128) { W2h[t] = (f16)W2[t]; return; }
    t -= 128 * 128;
    if (t < 16 * 128) {
        int r = t / 128, k = t % 128;
        W3p[t] = (f16)(r < 3 ? W3[r * 128 + k] : 0.f);
        return;
    }
    t -= 16 * 128;
    if (t < 6 * LINE_ELEMS) {
        int plane = t / LINE_ELEMS;
        int rem = t % LINE_ELEMS;
        int l = rem / 16, c = rem % 16;
        const float* src = (plane < 3) ? dlines + plane * 2048 : clines + (plane - 3) * 2048;
        linesT[t] = src[c * 128 + l];
    }
}

// ---------------------------------------------------------------------------
// Prep kernel 2: transpose planes [plane][c][y][x] -> planesT [plane][y][x][c16]
// One block per (plane, y). LDS-staged so both reads and writes coalesce.
// ---------------------------------------------------------------------------
__global__ void transpose_planes(const float* __restrict__ dplanes,
                                 const float* __restrict__ cplanes,
                                 float* __restrict__ planesT) {
    __shared__ float s[128 * 17];
    int b = blockIdx.x;
    int plane = b >> 7;
    int y = b & 127;
    const float* src = (plane < 3) ? dplanes + (size_t)plane * PLANE_ELEMS
                                   : cplanes + (size_t)(plane - 3) * PLANE_ELEMS;
    int tid = threadIdx.x;
#pragma unroll
    for (int it = 0; it < 8; it++) {
        int c = it * 2 + (tid >> 7);
        int x = tid & 127;
        s[x * 17 + c] = src[(size_t)c * 16384 + y * 128 + x];
    }
    __syncthreads();
    float* dst = planesT + ((size_t)plane * 128 + y) * 2048;
#pragma unroll
    for (int it = 0; it < 8; it++) {
        int d = it * 256 + tid;
        int x = d >> 4, c = d & 15;
        dst[d] = s[x * 17 + c];
    }
}

// ---------------------------------------------------------------------------
// Main fused kernel: sampling + PE -> f16 LDS tile -> 3-layer MLP via MFMA.
// 256 threads (4 waves), 256 points/block. LDS tile reused for feat/h1/h2.
// ---------------------------------------------------------------------------
__global__ __launch_bounds__(256, 2) void nerf_main(
    const float* __restrict__ pts, const float* __restrict__ rayu,
    const float* __restrict__ planesT, const float* __restrict__ linesT,
    const f16* __restrict__ W1p, const f16* __restrict__ W2h, const f16* __restrict__ W3p,
    const float* __restrict__ b1, const float* __restrict__ b2, const float* __restrict__ b3,
    float* __restrict__ out, int N) {
    __shared__ __align__(16) f16 tile[TP * FSTR];
    const int tid = threadIdx.x;
    const int p0 = blockIdx.x * TP;
    const int p = p0 + tid;

    // ---------------- phase 1: sampling + positional encoding ----------------
    {
        float g0 = pts[3 * p + 0], g1 = pts[3 * p + 1], g2 = pts[3 * p + 2];
        float rx = rayu[3 * p + 0], ry = rayu[3 * p + 1], rz = rayu[3 * p + 2];
        float g[3] = {g0, g1, g2};
        float sigma = 0.f;
        f16* frow = &tile[tid * FSTR];
#pragma unroll
        for (int i = 0; i < 3; i++) {
            const int m0 = (i == 2) ? 1 : 0;          // MAT_MODE[i][0]
            const int m1 = (i == 0) ? 1 : 2;          // MAT_MODE[i][1]
            const int vm = 2 - i;                     // VEC_MODE[i]
            float fx = (g[m0] + 1.f) * 0.5f * 127.f;
            float fy = (g[m1] + 1.f) * 0.5f * 127.f;
            float fl = (g[vm] + 1.f) * 0.5f * 127.f;
            int ix0 = min(max((int)floorf(fx), 0), 127); int ix1 = min(ix0 + 1, 127);
            int iy0 = min(max((int)floorf(fy), 0), 127); int iy1 = min(iy0 + 1, 127);
            int il0 = min(max((int)floorf(fl), 0), 127); int il1 = min(il0 + 1, 127);
            float wx = fx - (float)ix0, wy = fy - (float)iy0, wl = fl - (float)il0;
            float w00 = (1.f - wx) * (1.f - wy), w01 = wx * (1.f - wy);
            float w10 = (1.f - wx) * wy, w11 = wx * wy;
            const float* Pd = planesT + (size_t)i * PLANE_ELEMS;
            const float* Pc = planesT + (size_t)(3 + i) * PLANE_ELEMS;
            const float* Ld = linesT + i * LINE_ELEMS;
            const float* Lc = linesT + (3 + i) * LINE_ELEMS;
            int o00 = (iy0 * 128 + ix0) * 16, o01 = (iy0 * 128 + ix1) * 16;
            int o10 = (iy1 * 128 + ix0) * 16, o11 = (iy1 * 128 + ix1) * 16;
#pragma unroll
            for (int q = 0; q < 4; q++) {
                int qo = 4 * q;
                float4 pd = bilerp4(ld4(Pd + o00 + qo), ld4(Pd + o01 + qo),
                                    ld4(Pd + o10 + qo), ld4(Pd + o11 + qo), w00, w01, w10, w11);
                float4 dl = lerp4(ld4(Ld + il0 * 16 + qo), ld4(Ld + il1 * 16 + qo), wl);
                sigma += pd.x * dl.x + pd.y * dl.y + pd.z * dl.z + pd.w * dl.w;
                float4 pc = bilerp4(ld4(Pc + o00 + qo), ld4(Pc + o01 + qo),
                                    ld4(Pc + o10 + qo), ld4(Pc + o11 + qo), w00, w01, w10, w11);
                float4 cl = lerp4(ld4(Lc + il0 * 16 + qo), ld4(Lc + il1 * 16 + qo), wl);
                frow[16 * i + qo + 0] = (f16)(pc.x * cl.x);
                frow[16 * i + qo + 1] = (f16)(pc.y * cl.y);
                frow[16 * i + qo + 2] = (f16)(pc.z * cl.z);
                frow[16 * i + qo + 3] = (f16)(pc.w * cl.w);
            }
        }
        frow[48] = (f16)rx; frow[49] = (f16)ry; frow[50] = (f16)rz;
        float rv[3] = {rx, ry, rz};
#pragma unroll
        for (int d = 0; d < 3; d++) {
            float f = rv[d] * PI_F;
#pragma unroll
            for (int k = 0; k < 6; k++) {
                frow[51 + 12 * d + k] = (f16)__sinf(f);
                frow[51 + 12 * d + 6 + k] = (f16)__cosf(f);
                f = f + f;
            }
        }
#pragma unroll
        for (int c = 87; c < 96; c++) frow[c] = (f16)0.f;
        out[3 * N + p] = sigma;
    }
    __syncthreads();

    // ---------------- phase 2: MLP via MFMA ----------------
    const int w = tid >> 6, l = tid & 63, ar = l & 15, kg = l >> 4;
    const int col0 = 32 * w + ar;        // this wave's n-tiles: 2w, 2w+1
    const int col1 = 32 * w + 16 + ar;

    f32x4 acc[16][2];

    // ---- L1: feat[256x96] @ W1p^T -> h1[256x128] ----
    {
        f16x8 bfr0[3], bfr1[3];
#pragma unroll
        for (int k = 0; k < 3; k++) {
            bfr0[k] = *(const f16x8*)(W1p + col0 * 96 + 32 * k + 8 * kg);
            bfr1[k] = *(const f16x8*)(W1p + col1 * 96 + 32 * k + 8 * kg);
        }
        float bias0 = b1[col0], bias1 = b1[col1];
#pragma unroll
        for (int m = 0; m < 16; m++) {
            acc[m][0] = (f32x4){bias0, bias0, bias0, bias0};
            acc[m][1] = (f32x4){bias1, bias1, bias1, bias1};
        }
#pragma unroll
        for (int m = 0; m < 16; m++) {
            const f16* arow = &tile[(16 * m + ar) * FSTR + 8 * kg];
#pragma unroll
            for (int k = 0; k < 3; k++) {
                f16x8 a = *(const f16x8*)(arow + 32 * k);
                acc[m][0] = __builtin_amdgcn_mfma_f32_16x16x32_f16(a, bfr0[k], acc[m][0], 0, 0, 0);
                acc[m][1] = __builtin_amdgcn_mfma_f32_16x16x32_f16(a, bfr1[k], acc[m][1], 0, 0, 0);
            }
        }
    }
    __syncthreads();
#pragma unroll
    for (int m = 0; m < 16; m++)
#pragma unroll
        for (int j = 0; j < 4; j++) {
            int row = 16 * m + 4 * kg + j;
            tile[row * FSTR + col0] = (f16)fmaxf(acc[m][0][j], 0.f);
            tile[row * FSTR + col1] = (f16)fmaxf(acc[m][1][j], 0.f);
        }
    __syncthreads();

    // ---- L2: h1[256x128] @ W2^T -> h2[256x128] ----
    {
        f16x8 bfr0[4], bfr1[4];
#pragma unroll
        for (int k = 0; k < 4; k++) {
            bfr0[k] = *(const f16x8*)(W2h + col0 * 128 + 32 * k + 8 * kg);
            bfr1[k] = *(const f16x8*)(W2h + col1 * 128 + 32 * k + 8 * kg);
        }
        float bias0 = b2[col0], bias1 = b2[col1];
#pragma unroll
        for (int m = 0; m < 16; m++) {
            acc[m][0] = (f32x4){bias0, bias0, bias0, bias0};
            acc[m][1] = (f32x4){bias1, bias1, bias1, bias1};
        }
#pragma unroll
        for (int m = 0; m < 16; m++) {
            const f16* arow = &tile[(16 * m + ar) * FSTR + 8 * kg];
#pragma unroll
            for (int k = 0; k < 4; k++) {
                f16x8 a = *(const f16x8*)(arow + 32 * k);
                acc[m][0] = __builtin_amdgcn_mfma_f32_16x16x32_f16(a, bfr0[k], acc[m][0], 0, 0, 0);
                acc[m][1] = __builtin_amdgcn_mfma_f32_16x16x32_f16(a, bfr1[k], acc[m][1], 0, 0, 0);
            }
        }
    }
    __syncthreads();
#pragma unroll
    for (int m = 0; m < 16; m++)
#pragma unroll
        for (int j = 0; j < 4; j++) {
            int row = 16 * m + 4 * kg + j;
            tile[row * FSTR + col0] = (f16)fmaxf(acc[m][0][j], 0.f);
            tile[row * FSTR + col1] = (f16)fmaxf(acc[m][1][j], 0.f);
        }
    __syncthreads();

    // ---- L3: h2[256x128] @ W3p^T -> rgb (cols 0..2), each wave does 4 m-tiles ----
    {
        f16x8 bfr[4];
#pragma unroll
        for (int k = 0; k < 4; k++)
            bfr[k] = *(const f16x8*)(W3p + ar * 128 + 32 * k + 8 * kg);
        float bias3 = (ar < 3) ? b3[ar] : 0.f;
        f32x4 a3[4];
#pragma unroll
        for (int mm = 0; mm < 4; mm++) a3[mm] = (f32x4){bias3, bias3, bias3, bias3};
#pragma unroll
        for (int mm = 0; mm < 4; mm++) {
            int m = 4 * w + mm;
            const f16* arow = &tile[(16 * m + ar) * FSTR + 8 * kg];
#pragma unroll
            for (int k = 0; k < 4; k++) {
                f16x8 a = *(const f16x8*)(arow + 32 * k);
                a3[mm] = __builtin_amdgcn_mfma_f32_16x16x32_f16(a, bfr[k], a3[mm], 0, 0, 0);
            }
        }
        if (ar < 3) {
#pragma unroll
            for (int mm = 0; mm < 4; mm++)
#pragma unroll
                for (int j = 0; j < 4; j++) {
                    int row = p0 + 16 * (4 * w + mm) + 4 * kg + j;
                    float v = a3[mm][j];
                    out[3 * row + ar] = 1.f / (1.f + __expf(-v));
                }
        }
    }
}

extern "C" void kernel_launch(void* const* d_in, const int* in_sizes, int n_in,
                              void* d_out, int out_size, void* d_ws, size_t ws_size,
                              hipStream_t stream) {
    const float* pts    = (const float*)d_in[0];
    const float* rayu   = (const float*)d_in[1];
    const float* dplanes = (const float*)d_in[2];
    const float* dlines  = (const float*)d_in[3];
    const float* cplanes = (const float*)d_in[4];
    const float* clines  = (const float*)d_in[5];
    const float* basisW  = (const float*)d_in[6];
    const float* W1 = (const float*)d_in[7];
    const float* b1 = (const float*)d_in[8];
    const float* W2 = (const float*)d_in[9];
    const float* b2 = (const float*)d_in[10];
    const float* W3 = (const float*)d_in[11];
    const float* b3 = (const float*)d_in[12];
    float* out = (float*)d_out;
    const int N = in_sizes[0] / 3;

    // workspace layout
    float* planesT = (float*)d_ws;                       // 6 * 128*128*16 f32
    float* linesT = planesT + 6 * PLANE_ELEMS;           // 6 * 128*16 f32
    f16* W1p = (f16*)(linesT + 6 * LINE_ELEMS);          // 128*96 f16
    f16* W2h = W1p + 128 * 96;                           // 128*128 f16
    f16* W3p = W2h + 128 * 128;                          // 16*128 f16

    prep_small<<<168, 256, 0, stream>>>(W1, basisW, W2, W3, dlines, clines,
                                        W1p, W2h, W3p, linesT);
    transpose_planes<<<768, 256, 0, stream>>>(dplanes, cplanes, planesT);
    nerf_main<<<N / TP, 256, 0, stream>>>(pts, rayu, planesT, linesT,
                                          W1p, W2h, W3p, b1, b2, b3, out, N);
}

// Round 2
// 215.057 us; speedup vs baseline: 1.5325x; 1.5325x over previous
//
#include <hip/hip_runtime.h>

typedef _Float16 f16;
typedef f16 f16x8 __attribute__((ext_vector_type(8)));
typedef float f32x4 __attribute__((ext_vector_type(4)));

#define PI_F 3.14159265358979323846f

constexpr int TP = 256;          // points per block
constexpr int FSTR = 136;        // LDS row stride in f16 (272 B, 16B-aligned, bank-skewed)
constexpr int PLANE_ELEMS = 128 * 128 * 16;   // per-plane f32 elems in the INPUT
constexpr int IPLANE = 128 * 128 * 32;        // interleaved f16 elems per axis
constexpr int ILINE = 128 * 32;               // interleaved f16 elems per axis

// ---------------------------------------------------------------------------
// Prep kernel 1: fold basis into W1, convert weights to f16, interleave lines.
// W1p [128][96] f16: cols 0..47 = W1[:, :27] @ basis_W  (pl48 path)
//                    cols 48..50 = ray, 51..86 = enc, 87..95 = 0
// W2h [128][128] f16 = W2.  W3p [16][128] f16: rows 0..2 = W3, rest 0.
// linesI [axis][l][c32] f16: c<16 density ch c, c>=16 color ch c-16.
// ---------------------------------------------------------------------------
__global__ void prep_small(const float* __restrict__ W1, const float* __restrict__ basisW,
                           const float* __restrict__ W2, const float* __restrict__ W3,
                           const float* __restrict__ dlines, const float* __restrict__ clines,
                           f16* __restrict__ W1p, f16* __restrict__ W2h, f16* __restrict__ W3p,
                           f16* __restrict__ linesI) {
    int t = blockIdx.x * 256 + threadIdx.x;
    if (t < 128 * 96) {
        int r = t / 96, c = t % 96;
        float v = 0.f;
        if (c < 48) {
            for (int m = 0; m < 27; m++) v += W1[r * 66 + m] * basisW[m * 48 + c];
        } else if (c < 51) {
            v = W1[r * 66 + 27 + (c - 48)];
        } else if (c < 87) {
            v = W1[r * 66 + 30 + (c - 51)];
        }
        W1p[t] = (f16)v;
        return;
    }
    t -= 128 * 96;
    if (t < 128 * 128) { W2h[t] = (f16)W2[t]; return; }
    t -= 128 * 128;
    if (t < 16 * 128) {
        int r = t / 128, k = t % 128;
        W3p[t] = (f16)(r < 3 ? W3[r * 128 + k] : 0.f);
        return;
    }
    t -= 16 * 128;
    if (t < 3 * ILINE) {
        int axis = t / ILINE;
        int rem = t % ILINE;
        int l = rem / 32, c = rem % 32;
        float v = (c < 16) ? dlines[axis * 2048 + c * 128 + l]
                           : clines[axis * 2048 + (c - 16) * 128 + l];
        linesI[t] = (f16)v;
    }
}

// ---------------------------------------------------------------------------
// Prep kernel 2: [plane][c][y][x] f32 (density+color) -> planesI f16
// [axis][y][x][c32] with c<16 = density, c>=16 = color. 3 MB total ->
// resident in each XCD's 4 MiB L2. One block per (axis, y), LDS-staged.
// ---------------------------------------------------------------------------
__global__ void interleave_planes(const float* __restrict__ dplanes,
                                  const float* __restrict__ cplanes,
                                  f16* __restrict__ planesI) {
    __shared__ f16 s[128 * 34];
    int b = blockIdx.x;
    int axis = b >> 7;
    int y = b & 127;
    const float* dsrc = dplanes + (size_t)axis * PLANE_ELEMS + y * 128;
    const float* csrc = cplanes + (size_t)axis * PLANE_ELEMS + y * 128;
    int tid = threadIdx.x;
#pragma unroll
    for (int it = 0; it < 8; it++) {
        int c = it * 2 + (tid >> 7);
        int x = tid & 127;
        s[x * 34 + c]      = (f16)dsrc[(size_t)c * 16384 + x];
        s[x * 34 + 16 + c] = (f16)csrc[(size_t)c * 16384 + x];
    }
    __syncthreads();
    f16* dst = planesI + (size_t)(axis * 128 + y) * (128 * 32);
#pragma unroll
    for (int it = 0; it < 8; it++) {
        int d = it * 256 + tid;           // u32 index into 128*32 f16
        int x = d >> 4, cp = (d & 15) * 2;
        dst[2 * d]     = s[x * 34 + cp];
        dst[2 * d + 1] = s[x * 34 + cp + 1];
    }
}

// ---------------------------------------------------------------------------
// Main fused kernel: f16 gather + PE -> f16 LDS tile -> 3-layer MLP via MFMA.
// ---------------------------------------------------------------------------
__global__ __launch_bounds__(256, 2) void nerf_main(
    const float* __restrict__ pts, const float* __restrict__ rayu,
    const f16* __restrict__ planesI, const f16* __restrict__ linesI,
    const f16* __restrict__ W1p, const f16* __restrict__ W2h, const f16* __restrict__ W3p,
    const float* __restrict__ b1, const float* __restrict__ b2, const float* __restrict__ b3,
    float* __restrict__ out, int N) {
    __shared__ __align__(16) f16 tile[TP * FSTR];
    const int tid = threadIdx.x;
    const int p0 = blockIdx.x * TP;
    const int p = p0 + tid;

    // ---------------- phase 1: sampling + positional encoding ----------------
    {
        float g0 = pts[3 * p + 0], g1 = pts[3 * p + 1], g2 = pts[3 * p + 2];
        float rx = rayu[3 * p + 0], ry = rayu[3 * p + 1], rz = rayu[3 * p + 2];
        float g[3] = {g0, g1, g2};
        float sigma = 0.f;
        f16* frow = &tile[tid * FSTR];
#pragma unroll
        for (int i = 0; i < 3; i++) {
            const int m0 = (i == 2) ? 1 : 0;          // MAT_MODE[i][0]
            const int m1 = (i == 0) ? 1 : 2;          // MAT_MODE[i][1]
            const int vm = 2 - i;                     // VEC_MODE[i]
            float fx = (g[m0] + 1.f) * 0.5f * 127.f;
            float fy = (g[m1] + 1.f) * 0.5f * 127.f;
            float fl = (g[vm] + 1.f) * 0.5f * 127.f;
            int ix0 = min(max((int)floorf(fx), 0), 127); int ix1 = min(ix0 + 1, 127);
            int iy0 = min(max((int)floorf(fy), 0), 127); int iy1 = min(iy0 + 1, 127);
            int il0 = min(max((int)floorf(fl), 0), 127); int il1 = min(il0 + 1, 127);
            float wx = fx - (float)ix0, wy = fy - (float)iy0, wl = fl - (float)il0;
            f16 w00 = (f16)((1.f - wx) * (1.f - wy));
            f16 w01 = (f16)(wx * (1.f - wy));
            f16 w10 = (f16)((1.f - wx) * wy);
            f16 w11 = (f16)(wx * wy);
            f16 wl1 = (f16)(1.f - wl), wlh = (f16)wl;
            const f16* c00 = planesI + ((i * 128 + iy0) * 128 + ix0) * 32;
            const f16* c01 = planesI + ((i * 128 + iy0) * 128 + ix1) * 32;
            const f16* c10 = planesI + ((i * 128 + iy1) * 128 + ix0) * 32;
            const f16* c11 = planesI + ((i * 128 + iy1) * 128 + ix1) * 32;
            const f16* l0 = linesI + (i * 128 + il0) * 32;
            const f16* l1 = linesI + (i * 128 + il1) * 32;
#pragma unroll
            for (int q = 0; q < 4; q++) {
                f16x8 v00 = *(const f16x8*)(c00 + 8 * q);
                f16x8 v01 = *(const f16x8*)(c01 + 8 * q);
                f16x8 v10 = *(const f16x8*)(c10 + 8 * q);
                f16x8 v11 = *(const f16x8*)(c11 + 8 * q);
                f16x8 pb = v00 * w00 + v01 * w01 + v10 * w10 + v11 * w11;
                f16x8 lv = *(const f16x8*)(l0 + 8 * q) * wl1 + *(const f16x8*)(l1 + 8 * q) * wlh;
                if (q < 2) {
#pragma unroll
                    for (int e = 0; e < 8; e++) sigma += (float)pb[e] * (float)lv[e];
                } else {
                    *(f16x8*)(frow + 16 * i + 8 * (q - 2)) = pb * lv;
                }
            }
        }
        frow[48] = (f16)rx; frow[49] = (f16)ry; frow[50] = (f16)rz;
        float rv[3] = {rx, ry, rz};
#pragma unroll
        for (int d = 0; d < 3; d++) {
            float f = rv[d] * PI_F;
#pragma unroll
            for (int k = 0; k < 6; k++) {
                frow[51 + 12 * d + k] = (f16)__sinf(f);
                frow[51 + 12 * d + 6 + k] = (f16)__cosf(f);
                f = f + f;
            }
        }
#pragma unroll
        for (int c = 87; c < 96; c++) frow[c] = (f16)0.f;
        out[3 * N + p] = sigma;
    }
    __syncthreads();

    // ---------------- phase 2: MLP via MFMA ----------------
    const int w = tid >> 6, l = tid & 63, ar = l & 15, kg = l >> 4;
    const int col0 = 32 * w + ar;
    const int col1 = 32 * w + 16 + ar;

    f32x4 acc[16][2];

    // ---- L1: feat[256x96] @ W1p^T -> h1[256x128] ----
    {
        f16x8 bfr0[3], bfr1[3];
#pragma unroll
        for (int k = 0; k < 3; k++) {
            bfr0[k] = *(const f16x8*)(W1p + col0 * 96 + 32 * k + 8 * kg);
            bfr1[k] = *(const f16x8*)(W1p + col1 * 96 + 32 * k + 8 * kg);
        }
        float bias0 = b1[col0], bias1 = b1[col1];
#pragma unroll
        for (int m = 0; m < 16; m++) {
            acc[m][0] = (f32x4){bias0, bias0, bias0, bias0};
            acc[m][1] = (f32x4){bias1, bias1, bias1, bias1};
        }
#pragma unroll
        for (int m = 0; m < 16; m++) {
            const f16* arow = &tile[(16 * m + ar) * FSTR + 8 * kg];
#pragma unroll
            for (int k = 0; k < 3; k++) {
                f16x8 a = *(const f16x8*)(arow + 32 * k);
                acc[m][0] = __builtin_amdgcn_mfma_f32_16x16x32_f16(a, bfr0[k], acc[m][0], 0, 0, 0);
                acc[m][1] = __builtin_amdgcn_mfma_f32_16x16x32_f16(a, bfr1[k], acc[m][1], 0, 0, 0);
            }
        }
    }
    __syncthreads();
#pragma unroll
    for (int m = 0; m < 16; m++)
#pragma unroll
        for (int j = 0; j < 4; j++) {
            int row = 16 * m + 4 * kg + j;
            tile[row * FSTR + col0] = (f16)fmaxf(acc[m][0][j], 0.f);
            tile[row * FSTR + col1] = (f16)fmaxf(acc[m][1][j], 0.f);
        }
    __syncthreads();

    // ---- L2: h1[256x128] @ W2^T -> h2[256x128] ----
    {
        f16x8 bfr0[4], bfr1[4];
#pragma unroll
        for (int k = 0; k < 4; k++) {
            bfr0[k] = *(const f16x8*)(W2h + col0 * 128 + 32 * k + 8 * kg);
            bfr1[k] = *(const f16x8*)(W2h + col1 * 128 + 32 * k + 8 * kg);
        }
        float bias0 = b2[col0], bias1 = b2[col1];
#pragma unroll
        for (int m = 0; m < 16; m++) {
            acc[m][0] = (f32x4){bias0, bias0, bias0, bias0};
            acc[m][1] = (f32x4){bias1, bias1, bias1, bias1};
        }
#pragma unroll
        for (int m = 0; m < 16; m++) {
            const f16* arow = &tile[(16 * m + ar) * FSTR + 8 * kg];
#pragma unroll
            for (int k = 0; k < 4; k++) {
                f16x8 a = *(const f16x8*)(arow + 32 * k);
                acc[m][0] = __builtin_amdgcn_mfma_f32_16x16x32_f16(a, bfr0[k], acc[m][0], 0, 0, 0);
                acc[m][1] = __builtin_amdgcn_mfma_f32_16x16x32_f16(a, bfr1[k], acc[m][1], 0, 0, 0);
            }
        }
    }
    __syncthreads();
#pragma unroll
    for (int m = 0; m < 16; m++)
#pragma unroll
        for (int j = 0; j < 4; j++) {
            int row = 16 * m + 4 * kg + j;
            tile[row * FSTR + col0] = (f16)fmaxf(acc[m][0][j], 0.f);
            tile[row * FSTR + col1] = (f16)fmaxf(acc[m][1][j], 0.f);
        }
    __syncthreads();

    // ---- L3: h2[256x128] @ W3p^T -> rgb ----
    {
        f16x8 bfr[4];
#pragma unroll
        for (int k = 0; k < 4; k++)
            bfr[k] = *(const f16x8*)(W3p + ar * 128 + 32 * k + 8 * kg);
        float bias3 = (ar < 3) ? b3[ar] : 0.f;
        f32x4 a3[4];
#pragma unroll
        for (int mm = 0; mm < 4; mm++) a3[mm] = (f32x4){bias3, bias3, bias3, bias3};
#pragma unroll
        for (int mm = 0; mm < 4; mm++) {
            int m = 4 * w + mm;
            const f16* arow = &tile[(16 * m + ar) * FSTR + 8 * kg];
#pragma unroll
            for (int k = 0; k < 4; k++) {
                f16x8 a = *(const f16x8*)(arow + 32 * k);
                a3[mm] = __builtin_amdgcn_mfma_f32_16x16x32_f16(a, bfr[k], a3[mm], 0, 0, 0);
            }
        }
        if (ar < 3) {
#pragma unroll
            for (int mm = 0; mm < 4; mm++)
#pragma unroll
                for (int j = 0; j < 4; j++) {
                    int row = p0 + 16 * (4 * w + mm) + 4 * kg + j;
                    float v = a3[mm][j];
                    out[3 * row + ar] = 1.f / (1.f + __expf(-v));
                }
        }
    }
}

extern "C" void kernel_launch(void* const* d_in, const int* in_sizes, int n_in,
                              void* d_out, int out_size, void* d_ws, size_t ws_size,
                              hipStream_t stream) {
    const float* pts    = (const float*)d_in[0];
    const float* rayu   = (const float*)d_in[1];
    const float* dplanes = (const float*)d_in[2];
    const float* dlines  = (const float*)d_in[3];
    const float* cplanes = (const float*)d_in[4];
    const float* clines  = (const float*)d_in[5];
    const float* basisW  = (const float*)d_in[6];
    const float* W1 = (const float*)d_in[7];
    const float* b1 = (const float*)d_in[8];
    const float* W2 = (const float*)d_in[9];
    const float* b2 = (const float*)d_in[10];
    const float* W3 = (const float*)d_in[11];
    const float* b3 = (const float*)d_in[12];
    float* out = (float*)d_out;
    const int N = in_sizes[0] / 3;

    // workspace layout (all f16)
    f16* planesI = (f16*)d_ws;                 // 3 * 128*128*32
    f16* linesI = planesI + 3 * IPLANE;        // 3 * 128*32
    f16* W1p = linesI + 3 * ILINE;             // 128*96
    f16* W2h = W1p + 128 * 96;                 // 128*128
    f16* W3p = W2h + 128 * 128;                // 16*128

    prep_small<<<168, 256, 0, stream>>>(W1, basisW, W2, W3, dlines, clines,
                                        W1p, W2h, W3p, linesI);
    interleave_planes<<<384, 256, 0, stream>>>(dplanes, cplanes, planesI);
    nerf_main<<<N / TP, 256, 0, stream>>>(pts, rayu, planesI, linesI,
                                          W1p, W2h, W3p, b1, b2, b3, out, N);
}